// Round 3
// baseline (249.518 us; speedup 1.0000x reference)
//
#include <hip/hip_runtime.h>

#define BB 64
#define SS 512
#define HH 768
#define EE 128
#define TT 4
#define H4 (HH / 4)      // 192 float4 lanes per row
#define NP (EE * TT)     // 512 (entity,token) pairs
#define BGRP 32          // batch rows per block
#define NBG (BB / BGRP)  // 2 batch groups
#define NEBLK (SS * NBG) // 1024 enhance blocks
#define NGBLK (EE * NBG) // 256 gather blocks

// emb[b,e,:] = type_table[type[b,e]] + conf[b,e]*conf_w + conf_b.
// Correction for one (b, match-list): sum_type_rows + csum*conf_w + n*conf_b.
__device__ __forceinline__ float4 corr_enh(
    int b, int n, const int* mlist_s,
    const int* __restrict__ entity_types, const float* __restrict__ conf,
    const float4* __restrict__ tt4, int tid, float4 wv, float4 bv) {
  float4 ts = make_float4(0.f, 0.f, 0.f, 0.f);
  float cs = 0.f;
  for (int j = 0; j < n; ++j) {
    const int e = mlist_s[j];
    const int ty = entity_types[b * EE + e];
    cs += conf[b * EE + e];
    const float4 tv = tt4[ty * H4 + tid];
    ts.x += tv.x;
    ts.y += tv.y;
    ts.z += tv.z;
    ts.w += tv.w;
  }
  const float fn = (float)n;
  float4 r;
  r.x = ts.x + fmaf(cs, wv.x, fn * bv.x);
  r.y = ts.y + fmaf(cs, wv.y, fn * bv.y);
  r.z = ts.z + fmaf(cs, wv.z, fn * bv.z);
  r.w = ts.w + fmaf(cs, wv.w, fn * bv.w);
  return r;
}

// ---------------------------------------------------------------------------
// One dispatch. Blocks [0,NEBLK): enhance for one s x 32 batch rows (match
// scan amortized 32x, b-loop unrolled 4x for 12 KB of loads in flight).
// Blocks [NEBLK,NEBLK+NGBLK): ee for one e x 32 batch rows via the analytic
// identity ee[b,e] = 0.25*sum_t(hidden[b,s_t] + sum_{p:tok[p]=s_t} emb[b,p/T])
// -- no dependency on the enhance pass; hidden re-reads are L3 hits.
// ---------------------------------------------------------------------------
__global__ __launch_bounds__(H4) void fused_kernel(
    const float* __restrict__ hidden,
    const int* __restrict__ entity_types,   // (B,E)
    const float* __restrict__ conf,         // (B,E)
    const int* __restrict__ ent_tokens,     // (E,T)
    const float* __restrict__ type_table,   // (5,H)
    const float* __restrict__ conf_w,       // (H)
    const float* __restrict__ conf_b,       // (H)
    float* __restrict__ enhanced,           // (B,S,H)
    float* __restrict__ ee) {               // (B,E,H)
  const int tid = threadIdx.x;  // 0..191
  const int blk = blockIdx.x;

  __shared__ int nmatch;
  __shared__ int mlist[NP];  // enhance: e; gather: e | (weight<<16)
  if (tid == 0) nmatch = 0;
  __syncthreads();

  const float4 wv = ((const float4*)conf_w)[tid];
  const float4 bv = ((const float4*)conf_b)[tid];
  const float4* tt4 = (const float4*)type_table;
  const float4* hp = (const float4*)hidden;

  if (blk < NEBLK) {
    // ------------------------- enhance path -------------------------------
    const int s = blk >> 1;                  // / NBG
    const int b0 = (blk & (NBG - 1)) * BGRP;

    for (int p = tid; p < NP; p += H4)
      if (ent_tokens[p] == s) mlist[atomicAdd(&nmatch, 1)] = p >> 2;
    __syncthreads();
    const int n = nmatch;

    float4* out4 = (float4*)enhanced;
    for (int bb = 0; bb < BGRP; bb += 4) {
      const int b = b0 + bb;
      const size_t r0 = ((size_t)(b + 0) * SS + s) * H4 + tid;
      const size_t r1 = ((size_t)(b + 1) * SS + s) * H4 + tid;
      const size_t r2 = ((size_t)(b + 2) * SS + s) * H4 + tid;
      const size_t r3 = ((size_t)(b + 3) * SS + s) * H4 + tid;
      // 4 independent HBM loads in flight while corrections compute (L1 work)
      float4 v0 = hp[r0];
      float4 v1 = hp[r1];
      float4 v2 = hp[r2];
      float4 v3 = hp[r3];
      const float4 c0 = corr_enh(b + 0, n, mlist, entity_types, conf, tt4, tid, wv, bv);
      const float4 c1 = corr_enh(b + 1, n, mlist, entity_types, conf, tt4, tid, wv, bv);
      const float4 c2 = corr_enh(b + 2, n, mlist, entity_types, conf, tt4, tid, wv, bv);
      const float4 c3 = corr_enh(b + 3, n, mlist, entity_types, conf, tt4, tid, wv, bv);
      v0.x += c0.x; v0.y += c0.y; v0.z += c0.z; v0.w += c0.w;
      v1.x += c1.x; v1.y += c1.y; v1.z += c1.z; v1.w += c1.w;
      v2.x += c2.x; v2.y += c2.y; v2.z += c2.z; v2.w += c2.w;
      v3.x += c3.x; v3.y += c3.y; v3.z += c3.z; v3.w += c3.w;
      out4[r0] = v0;
      out4[r1] = v1;
      out4[r2] = v2;
      out4[r3] = v3;
    }
  } else {
    // ------------------------ gather/mean path ----------------------------
    const int g = blk - NEBLK;
    const int e = g >> 1;                    // / NBG
    const int b0 = (g & (NBG - 1)) * BGRP;

    const int s0 = ent_tokens[e * TT + 0];
    const int s1 = ent_tokens[e * TT + 1];
    const int s2 = ent_tokens[e * TT + 2];
    const int s3 = ent_tokens[e * TT + 3];

    // weight w = how many of this entity's 4 tokens pair p lands on
    for (int p = tid; p < NP; p += H4) {
      const int tok = ent_tokens[p];
      const int w = (tok == s0) + (tok == s1) + (tok == s2) + (tok == s3);
      if (w) mlist[atomicAdd(&nmatch, 1)] = (p >> 2) | (w << 16);
    }
    __syncthreads();
    const int n = nmatch;

    float4* ee4 = (float4*)ee;
    for (int bb = 0; bb < BGRP; ++bb) {
      const int b = b0 + bb;
      const float4* hb = hp + (size_t)b * SS * H4;
      const float4 v0 = hb[(size_t)s0 * H4 + tid];
      const float4 v1 = hb[(size_t)s1 * H4 + tid];
      const float4 v2 = hb[(size_t)s2 * H4 + tid];
      const float4 v3 = hb[(size_t)s3 * H4 + tid];
      float4 ts = make_float4(0.f, 0.f, 0.f, 0.f);
      float cs = 0.f, ws = 0.f;
      for (int j = 0; j < n; ++j) {
        const int packed = mlist[j];
        const int e2 = packed & 0xffff;
        const float fw = (float)(packed >> 16);
        const int ty = entity_types[b * EE + e2];
        cs += fw * conf[b * EE + e2];
        ws += fw;
        const float4 tv = tt4[ty * H4 + tid];
        ts.x += fw * tv.x;
        ts.y += fw * tv.y;
        ts.z += fw * tv.z;
        ts.w += fw * tv.w;
      }
      float4 o;
      o.x = 0.25f * ((v0.x + v1.x) + (v2.x + v3.x) + ts.x + fmaf(cs, wv.x, ws * bv.x));
      o.y = 0.25f * ((v0.y + v1.y) + (v2.y + v3.y) + ts.y + fmaf(cs, wv.y, ws * bv.y));
      o.z = 0.25f * ((v0.z + v1.z) + (v2.z + v3.z) + ts.z + fmaf(cs, wv.z, ws * bv.z));
      o.w = 0.25f * ((v0.w + v1.w) + (v2.w + v3.w) + ts.w + fmaf(cs, wv.w, ws * bv.w));
      ee4[(size_t)(b * EE + e) * H4 + tid] = o;
    }
  }
}

extern "C" void kernel_launch(void* const* d_in, const int* in_sizes, int n_in,
                              void* d_out, int out_size, void* d_ws,
                              size_t ws_size, hipStream_t stream) {
  const float* hidden = (const float*)d_in[0];      // (B,S,H) fp32
  const int* entity_types = (const int*)d_in[1];    // (B,E) i32
  const float* conf = (const float*)d_in[2];        // (B,E) fp32
  const int* ent_tokens = (const int*)d_in[3];      // (E,T) i32
  const float* type_table = (const float*)d_in[4];  // (5,H) fp32
  const float* conf_w = (const float*)d_in[5];      // (1,H) fp32
  const float* conf_b = (const float*)d_in[6];      // (H) fp32

  float* enhanced = (float*)d_out;                   // (B,S,H)
  float* ee = (float*)d_out + (size_t)BB * SS * HH;  // (B,E,H)

  fused_kernel<<<NEBLK + NGBLK, H4, 0, stream>>>(
      hidden, entity_types, conf, ent_tokens, type_table, conf_w, conf_b,
      enhanced, ee);
}

// Round 4
// 227.750 us; speedup vs baseline: 1.0956x; 1.0956x over previous
//
#include <hip/hip_runtime.h>

#define BB 64
#define SS 512
#define HH 768
#define EE 128
#define TT 4
#define H4 (HH / 4)      // 192 float4 lanes per row
#define NP (EE * TT)     // 512 (entity,token) pairs
#define NROWS (BB * SS)  // 32768 enhance rows

// ---------------------------------------------------------------------------
// Kernel A: counting-sort ent_tokens (512 pairs) by token position s.
// offsets[S+1], entries[512] (entity per pair; duplicates preserved).
// One block, 512 threads, ~4 us. Rebuilt every launch (d_ws re-poisoned).
// ---------------------------------------------------------------------------
__global__ __launch_bounds__(SS) void build_index_kernel(
    const int* __restrict__ ent_tokens,
    int* __restrict__ offsets,    // S+1 ints
    int* __restrict__ entries) {  // E*T ints
  __shared__ int cnt[SS];
  __shared__ int scan[SS];
  __shared__ int pos[SS];
  const int tid = threadIdx.x;  // 0..511

  cnt[tid] = 0;
  __syncthreads();

  const int s = ent_tokens[tid];
  atomicAdd(&cnt[s], 1);
  __syncthreads();

  scan[tid] = cnt[tid];
  __syncthreads();
  for (int off = 1; off < SS; off <<= 1) {
    int add = (tid >= off) ? scan[tid - off] : 0;
    __syncthreads();
    scan[tid] += add;
    __syncthreads();
  }

  const int excl = scan[tid] - cnt[tid];
  offsets[tid] = excl;
  if (tid == 0) offsets[SS] = NP;
  pos[tid] = excl;
  __syncthreads();

  const int p = atomicAdd(&pos[s], 1);
  entries[p] = tid >> 2;  // e = pair / T
}

// ---------------------------------------------------------------------------
// Kernel B: one dispatch, no LDS / barriers / atomics -- pure streaming.
//   Blocks [0, NROWS): enhanced[b,s,:] = hidden[b,s,:] + bucket(s) corrections
//     (round-0 enhance shape: per-row block, 192 thr x float4, two scalar
//      offset reads, n~1 avg correction entries, all L1/L2-hot).
//   Blocks [NROWS, NROWS+B*E): ee[b,e,:] computed ANALYTICALLY from hidden +
//     buckets of the entity's 4 tokens (== mean of enhanced rows, but with
//     no dependency on the enhance pass; hidden re-reads are L3 hits since
//     gather blocks sit at the grid tail).
// ---------------------------------------------------------------------------
__global__ __launch_bounds__(H4) void fused_kernel(
    const float* __restrict__ hidden,
    const int* __restrict__ entity_types,   // (B,E)
    const float* __restrict__ conf,         // (B,E)
    const int* __restrict__ ent_tokens,     // (E,T)
    const float* __restrict__ type_table,   // (5,H)
    const float* __restrict__ conf_w,       // (H)
    const float* __restrict__ conf_b,       // (H)
    const int* __restrict__ offsets,
    const int* __restrict__ entries,
    float* __restrict__ enhanced,           // (B,S,H)
    float* __restrict__ ee) {               // (B,E,H)
  const int tid = threadIdx.x;  // 0..191
  const int blk = blockIdx.x;
  const float4* tt4 = (const float4*)type_table;
  const float4* hp = (const float4*)hidden;

  if (blk < NROWS) {
    // ------------------------- enhance path -------------------------------
    const int row = blk;
    const int b = row >> 9;          // / SS
    const int s = row & (SS - 1);

    float4 acc = hp[(size_t)row * H4 + tid];

    const int o0 = offsets[s];
    const int o1 = offsets[s + 1];
    if (o1 > o0) {
      const float4 wv = ((const float4*)conf_w)[tid];
      const float4 bv = ((const float4*)conf_b)[tid];
      float4 ts = make_float4(0.f, 0.f, 0.f, 0.f);
      float cs = 0.f;
      for (int j = o0; j < o1; ++j) {
        const int e = entries[j];
        const int ty = entity_types[b * EE + e];
        cs += conf[b * EE + e];
        const float4 tv = tt4[ty * H4 + tid];
        ts.x += tv.x;
        ts.y += tv.y;
        ts.z += tv.z;
        ts.w += tv.w;
      }
      const float fn = (float)(o1 - o0);
      acc.x += ts.x + fmaf(cs, wv.x, fn * bv.x);
      acc.y += ts.y + fmaf(cs, wv.y, fn * bv.y);
      acc.z += ts.z + fmaf(cs, wv.z, fn * bv.z);
      acc.w += ts.w + fmaf(cs, wv.w, fn * bv.w);
    }
    ((float4*)enhanced)[(size_t)row * H4 + tid] = acc;
  } else {
    // ------------------------ gather/mean path ----------------------------
    const int be = blk - NROWS;
    const int b = be >> 7;           // / EE
    const int e = be & (EE - 1);

    const int s0 = ent_tokens[e * TT + 0];
    const int s1 = ent_tokens[e * TT + 1];
    const int s2 = ent_tokens[e * TT + 2];
    const int s3 = ent_tokens[e * TT + 3];

    const float4* hb = hp + (size_t)b * SS * H4;
    const float4 v0 = hb[(size_t)s0 * H4 + tid];
    const float4 v1 = hb[(size_t)s1 * H4 + tid];
    const float4 v2 = hb[(size_t)s2 * H4 + tid];
    const float4 v3 = hb[(size_t)s3 * H4 + tid];
    float4 acc;
    acc.x = (v0.x + v1.x) + (v2.x + v3.x);
    acc.y = (v0.y + v1.y) + (v2.y + v3.y);
    acc.z = (v0.z + v1.z) + (v2.z + v3.z);
    acc.w = (v0.w + v1.w) + (v2.w + v3.w);

    const float4 wv = ((const float4*)conf_w)[tid];
    const float4 bv = ((const float4*)conf_b)[tid];
    float4 ts = make_float4(0.f, 0.f, 0.f, 0.f);
    float cs = 0.f;
    float ws = 0.f;
    // buckets of the 4 tokens reproduce exactly the pairs summed into the
    // 4 enhanced rows (duplicates included)
    const int sv[TT] = {s0, s1, s2, s3};
    for (int t = 0; t < TT; ++t) {
      const int st = sv[t];
      const int o0 = offsets[st];
      const int o1 = offsets[st + 1];
      for (int j = o0; j < o1; ++j) {
        const int e2 = entries[j];
        const int ty = entity_types[b * EE + e2];
        cs += conf[b * EE + e2];
        ws += 1.f;
        const float4 tv = tt4[ty * H4 + tid];
        ts.x += tv.x;
        ts.y += tv.y;
        ts.z += tv.z;
        ts.w += tv.w;
      }
    }
    float4 o;
    o.x = 0.25f * (acc.x + ts.x + fmaf(cs, wv.x, ws * bv.x));
    o.y = 0.25f * (acc.y + ts.y + fmaf(cs, wv.y, ws * bv.y));
    o.z = 0.25f * (acc.z + ts.z + fmaf(cs, wv.z, ws * bv.z));
    o.w = 0.25f * (acc.w + ts.w + fmaf(cs, wv.w, ws * bv.w));
    ((float4*)ee)[(size_t)be * H4 + tid] = o;
  }
}

extern "C" void kernel_launch(void* const* d_in, const int* in_sizes, int n_in,
                              void* d_out, int out_size, void* d_ws,
                              size_t ws_size, hipStream_t stream) {
  const float* hidden = (const float*)d_in[0];      // (B,S,H) fp32
  const int* entity_types = (const int*)d_in[1];    // (B,E) i32
  const float* conf = (const float*)d_in[2];        // (B,E) fp32
  const int* ent_tokens = (const int*)d_in[3];      // (E,T) i32
  const float* type_table = (const float*)d_in[4];  // (5,H) fp32
  const float* conf_w = (const float*)d_in[5];      // (1,H) fp32
  const float* conf_b = (const float*)d_in[6];      // (H) fp32

  float* enhanced = (float*)d_out;                   // (B,S,H)
  float* ee = (float*)d_out + (size_t)BB * SS * HH;  // (B,E,H)

  int* offsets = (int*)d_ws;          // S+1
  int* entries = offsets + (SS + 1);  // E*T

  build_index_kernel<<<1, SS, 0, stream>>>(ent_tokens, offsets, entries);
  fused_kernel<<<NROWS + BB * EE, H4, 0, stream>>>(
      hidden, entity_types, conf, ent_tokens, type_table, conf_w, conf_b,
      offsets, entries, enhanced, ee);
}

// Round 5
// 223.146 us; speedup vs baseline: 1.1182x; 1.0206x over previous
//
#include <hip/hip_runtime.h>

#define BB 64
#define SS 512
#define HH 768
#define EE 128
#define TT 4
#define H4 (HH / 4)       // 192 float4 lanes per row
#define NP (EE * TT)      // 512 (entity,token) pairs
#define NROWS (BB * SS)   // 32768 enhance rows
#define NEBLK (NROWS / 4) // 8192 enhance blocks (4 contiguous rows each)
#define NGBLK (BB * EE)   // 8192 gather blocks (1 row each)

// ---------------------------------------------------------------------------
// Kernel A: counting-sort ent_tokens (512 pairs) by token position s.
// offsets[S+1], entries[512] (entity per pair; duplicates preserved).
// One block, 512 threads, ~4 us. Rebuilt every launch (d_ws re-poisoned).
// ---------------------------------------------------------------------------
__global__ __launch_bounds__(SS) void build_index_kernel(
    const int* __restrict__ ent_tokens,
    int* __restrict__ offsets,    // S+1 ints
    int* __restrict__ entries) {  // E*T ints
  __shared__ int cnt[SS];
  __shared__ int scan[SS];
  __shared__ int pos[SS];
  const int tid = threadIdx.x;  // 0..511

  cnt[tid] = 0;
  __syncthreads();

  const int s = ent_tokens[tid];
  atomicAdd(&cnt[s], 1);
  __syncthreads();

  scan[tid] = cnt[tid];
  __syncthreads();
  for (int off = 1; off < SS; off <<= 1) {
    int add = (tid >= off) ? scan[tid - off] : 0;
    __syncthreads();
    scan[tid] += add;
    __syncthreads();
  }

  const int excl = scan[tid] - cnt[tid];
  offsets[tid] = excl;
  if (tid == 0) offsets[SS] = NP;
  pos[tid] = excl;
  __syncthreads();

  const int p = atomicAdd(&pos[s], 1);
  entries[p] = tid >> 2;  // e = pair / T
}

// correction for one row: sum over bucket [o0,o1) of
//   type_table[type[b,e]] + conf[b,e]*conf_w + conf_b
__device__ __forceinline__ float4 corr(
    int b, int o0, int o1, const int* __restrict__ entries,
    const int* __restrict__ entity_types, const float* __restrict__ conf,
    const float4* __restrict__ tt4, int tid, float4 wv, float4 bv) {
  float4 ts = make_float4(0.f, 0.f, 0.f, 0.f);
  float cs = 0.f;
  for (int j = o0; j < o1; ++j) {
    const int e = entries[j];
    const int ty = entity_types[b * EE + e];
    cs += conf[b * EE + e];
    const float4 tv = tt4[ty * H4 + tid];
    ts.x += tv.x;
    ts.y += tv.y;
    ts.z += tv.z;
    ts.w += tv.w;
  }
  const float fn = (float)(o1 - o0);
  float4 r;
  r.x = ts.x + fmaf(cs, wv.x, fn * bv.x);
  r.y = ts.y + fmaf(cs, wv.y, fn * bv.y);
  r.z = ts.z + fmaf(cs, wv.z, fn * bv.z);
  r.w = ts.w + fmaf(cs, wv.w, fn * bv.w);
  return r;
}

// ---------------------------------------------------------------------------
// Kernel B: one dispatch, no LDS / barriers / atomics.
//   Blocks [0, NEBLK): enhance 4 CONTIGUOUS rows (same b, s0..s0+3):
//     12 KB contiguous load span issued up-front (4x per-wave MLP vs round 4),
//     4 independent bucket corrections, 12 KB contiguous store span.
//   Blocks [NEBLK, NEBLK+NGBLK): ee[b,e,:] analytically from hidden + the
//     buckets of the entity's 4 tokens (no dependency on enhance; 4 row
//     reads are L3 hits and already independent).
// ---------------------------------------------------------------------------
__global__ __launch_bounds__(H4) void fused_kernel(
    const float* __restrict__ hidden,
    const int* __restrict__ entity_types,   // (B,E)
    const float* __restrict__ conf,         // (B,E)
    const int* __restrict__ ent_tokens,     // (E,T)
    const float* __restrict__ type_table,   // (5,H)
    const float* __restrict__ conf_w,       // (H)
    const float* __restrict__ conf_b,       // (H)
    const int* __restrict__ offsets,
    const int* __restrict__ entries,
    float* __restrict__ enhanced,           // (B,S,H)
    float* __restrict__ ee) {               // (B,E,H)
  const int tid = threadIdx.x;  // 0..191
  const int blk = blockIdx.x;
  const float4* tt4 = (const float4*)type_table;
  const float4* hp = (const float4*)hidden;

  if (blk < NEBLK) {
    // ------------------------- enhance path -------------------------------
    const int row0 = blk << 2;       // 4-aligned => s0..s0+3 share b
    const int b = row0 >> 9;         // / SS
    const int s0 = row0 & (SS - 1);

    const size_t base = (size_t)row0 * H4 + tid;
    // 4 independent loads in flight (contiguous 12 KB span per block)
    float4 v0 = hp[base];
    float4 v1 = hp[base + H4];
    float4 v2 = hp[base + 2 * H4];
    float4 v3 = hp[base + 3 * H4];

    const int o0 = offsets[s0];
    const int o1 = offsets[s0 + 1];
    const int o2 = offsets[s0 + 2];
    const int o3 = offsets[s0 + 3];
    const int o4 = offsets[s0 + 4];

    if (o4 > o0) {  // any correction among the 4 rows
      const float4 wv = ((const float4*)conf_w)[tid];
      const float4 bv = ((const float4*)conf_b)[tid];
      if (o1 > o0) {
        const float4 c = corr(b, o0, o1, entries, entity_types, conf, tt4, tid, wv, bv);
        v0.x += c.x; v0.y += c.y; v0.z += c.z; v0.w += c.w;
      }
      if (o2 > o1) {
        const float4 c = corr(b, o1, o2, entries, entity_types, conf, tt4, tid, wv, bv);
        v1.x += c.x; v1.y += c.y; v1.z += c.z; v1.w += c.w;
      }
      if (o3 > o2) {
        const float4 c = corr(b, o2, o3, entries, entity_types, conf, tt4, tid, wv, bv);
        v2.x += c.x; v2.y += c.y; v2.z += c.z; v2.w += c.w;
      }
      if (o4 > o3) {
        const float4 c = corr(b, o3, o4, entries, entity_types, conf, tt4, tid, wv, bv);
        v3.x += c.x; v3.y += c.y; v3.z += c.z; v3.w += c.w;
      }
    }

    float4* out4 = (float4*)enhanced;
    out4[base] = v0;
    out4[base + H4] = v1;
    out4[base + 2 * H4] = v2;
    out4[base + 3 * H4] = v3;
  } else {
    // ------------------------ gather/mean path ----------------------------
    const int be = blk - NEBLK;
    const int b = be >> 7;           // / EE
    const int e = be & (EE - 1);

    const int s0 = ent_tokens[e * TT + 0];
    const int s1 = ent_tokens[e * TT + 1];
    const int s2 = ent_tokens[e * TT + 2];
    const int s3 = ent_tokens[e * TT + 3];

    const float4* hb = hp + (size_t)b * SS * H4;
    const float4 v0 = hb[(size_t)s0 * H4 + tid];
    const float4 v1 = hb[(size_t)s1 * H4 + tid];
    const float4 v2 = hb[(size_t)s2 * H4 + tid];
    const float4 v3 = hb[(size_t)s3 * H4 + tid];
    float4 acc;
    acc.x = (v0.x + v1.x) + (v2.x + v3.x);
    acc.y = (v0.y + v1.y) + (v2.y + v3.y);
    acc.z = (v0.z + v1.z) + (v2.z + v3.z);
    acc.w = (v0.w + v1.w) + (v2.w + v3.w);

    const float4 wv = ((const float4*)conf_w)[tid];
    const float4 bv = ((const float4*)conf_b)[tid];
    float4 ts = make_float4(0.f, 0.f, 0.f, 0.f);
    float cs = 0.f;
    float ws = 0.f;
    // buckets of the 4 tokens reproduce exactly the pairs summed into the
    // 4 enhanced rows (duplicates included)
    const int sa0 = s0, sa1 = s1, sa2 = s2, sa3 = s3;
#pragma unroll
    for (int t = 0; t < TT; ++t) {
      const int st = (t == 0) ? sa0 : (t == 1) ? sa1 : (t == 2) ? sa2 : sa3;
      const int oo0 = offsets[st];
      const int oo1 = offsets[st + 1];
      for (int j = oo0; j < oo1; ++j) {
        const int e2 = entries[j];
        const int ty = entity_types[b * EE + e2];
        cs += conf[b * EE + e2];
        ws += 1.f;
        const float4 tv = tt4[ty * H4 + tid];
        ts.x += tv.x;
        ts.y += tv.y;
        ts.z += tv.z;
        ts.w += tv.w;
      }
    }
    float4 o;
    o.x = 0.25f * (acc.x + ts.x + fmaf(cs, wv.x, ws * bv.x));
    o.y = 0.25f * (acc.y + ts.y + fmaf(cs, wv.y, ws * bv.y));
    o.z = 0.25f * (acc.z + ts.z + fmaf(cs, wv.z, ws * bv.z));
    o.w = 0.25f * (acc.w + ts.w + fmaf(cs, wv.w, ws * bv.w));
    ((float4*)ee)[(size_t)be * H4 + tid] = o;
  }
}

extern "C" void kernel_launch(void* const* d_in, const int* in_sizes, int n_in,
                              void* d_out, int out_size, void* d_ws,
                              size_t ws_size, hipStream_t stream) {
  const float* hidden = (const float*)d_in[0];      // (B,S,H) fp32
  const int* entity_types = (const int*)d_in[1];    // (B,E) i32
  const float* conf = (const float*)d_in[2];        // (B,E) fp32
  const int* ent_tokens = (const int*)d_in[3];      // (E,T) i32
  const float* type_table = (const float*)d_in[4];  // (5,H) fp32
  const float* conf_w = (const float*)d_in[5];      // (1,H) fp32
  const float* conf_b = (const float*)d_in[6];      // (H) fp32

  float* enhanced = (float*)d_out;                   // (B,S,H)
  float* ee = (float*)d_out + (size_t)BB * SS * HH;  // (B,E,H)

  int* offsets = (int*)d_ws;          // S+1
  int* entries = offsets + (SS + 1);  // E*T

  build_index_kernel<<<1, SS, 0, stream>>>(ent_tokens, offsets, entries);
  fused_kernel<<<NEBLK + NGBLK, H4, 0, stream>>>(
      hidden, entity_types, conf, ent_tokens, type_table, conf_w, conf_b,
      offsets, entries, enhanced, ee);
}